// Round 1
// baseline (514.660 us; speedup 1.0000x reference)
//
#include <hip/hip_runtime.h>
#include <hip/hip_bf16.h>

// GraphSageLayer on MI355X. B=4, N=4096, D_IN=REP=D_OUT=128.
// proj (nodes->3 reps, bf16) -> agg (adj @ in_rep, adj^T @ out_rep) -> final (concat @ W_upd^T, tanh).
// All matmuls via v_mfma_f32_16x16x32_bf16; fp32 converted to bf16 in flight.
//
// R2: BK=128 epochs, epoch-ahead prefetch, LDS stride 136 (conflict-free b128),
//     paired-row ds_write_b32 for the transpose path.
// R3 (latency fix: agg was 181us vs 56us BW floor; Occ 19%, grid 512 = 2 blk/CU
//     was the cap -- VGPR 68 and LDS 34KB both allow 4 blk/CU):
//  - split-K=2: 1024 blocks (4/CU, 4 waves/SIMD), each does 16 epochs of one
//    K-half. adj/rep traffic unchanged. Partial sums stored fp32 to separate
//    half-buffers (no atomics, deterministic; bf16 rounding now happens only
//    once, in final's operand pack -> precision same or better).
//  - final consumes the halves as extra K-slices vs the SAME W_upd columns
//    (matmul is linear in upd): 12 A-loads, 20 B-slices.
//  - ws need 44MB; guarded fallback to the R2 split-1 path if ws is smaller.

typedef __attribute__((ext_vector_type(8))) short short8;
typedef __attribute__((ext_vector_type(4))) float f32x4;
typedef __attribute__((ext_vector_type(4))) unsigned short u16x4;

#define MFMA(a, b, c) __builtin_amdgcn_mfma_f32_16x16x32_bf16(a, b, c, 0, 0, 0)

__device__ __forceinline__ unsigned short f2bf(float x) {
  union { float f; unsigned u; } v; v.f = x;
  unsigned r = v.u + 0x7FFFu + ((v.u >> 16) & 1u);   // RNE to bf16
  return (unsigned short)(r >> 16);
}

__device__ __forceinline__ short8 pack8(float4 a, float4 b) {
  short8 v;
  v[0] = (short)f2bf(a.x); v[1] = (short)f2bf(a.y); v[2] = (short)f2bf(a.z); v[3] = (short)f2bf(a.w);
  v[4] = (short)f2bf(b.x); v[5] = (short)f2bf(b.y); v[6] = (short)f2bf(b.z); v[7] = (short)f2bf(b.w);
  return v;
}

// ---------------------------------------------------------------------------
// Kernel 1: projections. rep = elu(nodes @ W^T + b). grid=(256 m-tiles, 3).
// Per wave: m=16 nodes, n=128 r. All A-frags loaded up front, K unrolled.
// ---------------------------------------------------------------------------
__global__ __launch_bounds__(256) void proj_kernel(
    const float* __restrict__ nodes,   // [16384][128]
    const float* __restrict__ W_in, const float* __restrict__ b_in,
    const float* __restrict__ W_out, const float* __restrict__ b_out,
    const float* __restrict__ W_node, const float* __restrict__ b_node,
    unsigned short* __restrict__ in_rep_t,   // [4][128][4096]
    unsigned short* __restrict__ out_rep_t,  // [4][128][4096]
    unsigned short* __restrict__ node_rep)   // [4][4096][128]
{
  const int wsel = blockIdx.y;
  const float* W    = (wsel == 0) ? W_in  : (wsel == 1) ? W_out  : W_node;
  const float* bias = (wsel == 0) ? b_in  : (wsel == 1) ? b_out  : b_node;

  const int tid  = threadIdx.x;
  const int lane = tid & 63;
  const int w    = tid >> 6;
  const int q    = lane >> 4;
  const int r15  = lane & 15;
  const int m0   = blockIdx.x * 64 + w * 16;   // node base for this wave

  f32x4 acc[8];
#pragma unroll
  for (int nt = 0; nt < 8; ++nt) acc[nt] = (f32x4)0.0f;

  short8 a[4];
#pragma unroll
  for (int ks = 0; ks < 4; ++ks) {
    const float* p = nodes + (size_t)(m0 + r15) * 128 + ks * 32 + q * 8;
    a[ks] = pack8(*(const float4*)p, *(const float4*)(p + 4));
  }

#pragma unroll
  for (int ks = 0; ks < 4; ++ks)
#pragma unroll
    for (int nt = 0; nt < 8; ++nt) {
      const float* p = W + (size_t)(nt * 16 + r15) * 128 + ks * 32 + q * 8;
      short8 bv = pack8(*(const float4*)p, *(const float4*)(p + 4));
      acc[nt] = MFMA(a[ks], bv, acc[nt]);
    }

#pragma unroll
  for (int nt = 0; nt < 8; ++nt) {
    const int rcol = nt * 16 + r15;
    const float bv = bias[rcol];
    const int g0 = m0 + q * 4;   // global node of reg 0
    float x[4];
#pragma unroll
    for (int c = 0; c < 4; ++c) {
      float t = acc[nt][c] + bv;
      x[c] = (t > 0.f) ? t : (expf(t) - 1.f);   // ELU
    }
    if (wsel < 2) {
      unsigned short* rep = (wsel == 0) ? in_rep_t : out_rep_t;
      const int b = g0 >> 12, j = g0 & 4095;
      u16x4 o;
#pragma unroll
      for (int c = 0; c < 4; ++c) o[c] = f2bf(x[c]);
      *(u16x4*)&rep[((size_t)b << 19) + (size_t)rcol * 4096 + j] = o;
    } else {
#pragma unroll
      for (int c = 0; c < 4; ++c)
        node_rep[(size_t)(g0 + c) * 128 + rcol] = f2bf(x[c]);
    }
  }
}

// ---------------------------------------------------------------------------
// Kernel 2: aggregations.
//   !TC: in_agg[i,v]  = sum_j adj[b][i][j] * in_rep[j][v]
//    TC: out_agg[i,v] = sum_j adj[b][j][i] * out_rep[j][v]
// BK=128 epochs, double-buffered LDS [i=64][k=128] bf16, row stride 136 shorts
// (conflict-free b128 reads+writes). Prefetch next adj tile + next A-frags one
// full epoch ahead. MFMA-A = rep_t[b][v][j] (direct global, L2-hot);
// MFMA-B = LDS tile. D: row(m=v)=quad*4+reg, col(n=i)=lane&15.
// SPLIT: epochs [e0,e0+ne), fp32 f32x4 stores to a partial buffer.
// ---------------------------------------------------------------------------
#define AGG_BK 128
#define AGG_ST 136   // shorts per LDS row: 128 + 8 pad
#define AGG_BUF (64 * AGG_ST)

template <bool TC, bool SPLIT>
__device__ __forceinline__ void agg_body(
    const float* __restrict__ adjb,         // adj + b*2^24
    const unsigned short* __restrict__ rep, // rep_t + b*2^19
    void* __restrict__ agg,                 // bf16 (full) or fp32 (partial) + b*2^19
    unsigned short* lds,                    // [2][AGG_BUF]
    int n0, int e0, int ne)
{
  const int tid  = threadIdx.x;
  const int lane = tid & 63;
  const int w    = tid >> 6;
  const int q    = lane >> 4;
  const int r15  = lane & 15;

  const unsigned short* arow[2];
#pragma unroll
  for (int mt = 0; mt < 2; ++mt)
    arow[mt] = rep + (size_t)(w * 32 + mt * 16 + r15) * 4096 + q * 8;

  // staging geometry
  int sti, stko, j0 = 0;
  const float* ld0; const float* ld1 = nullptr;
  if (!TC) {              // tile adj[n0+i][e*128+k]: thread = row sti, 32 cols
    sti  = tid >> 2;                 // i in [0,64)
    stko = (tid & 3) * 32;           // k base {0,32,64,96}
    ld0  = adjb + (size_t)(n0 + sti) * 4096 + stko;
  } else {                // tile adj[e*128+j][n0+i]: thread = rows j0,j0+1 x 16 cols
    j0   = (tid >> 2) * 2;           // j in {0,2,...,126}
    sti  = (tid & 3) * 16;           // i base {0,16,32,48}
    ld0  = adjb + (size_t)j0 * 4096 + n0 + sti;
    ld1  = ld0 + 4096;
  }

  f32x4 acc[2][4];
#pragma unroll
  for (int mt = 0; mt < 2; ++mt)
#pragma unroll
    for (int nt = 0; nt < 4; ++nt) acc[mt][nt] = (f32x4)0.0f;

  float4 pf[8];
  short8 a_cur[8], a_nxt[8];

  auto stage_load = [&](int e) {
    if (!TC) {
      const float* p = ld0 + e * AGG_BK;
#pragma unroll
      for (int s = 0; s < 8; ++s) pf[s] = ((const float4*)p)[s];
    } else {
      const float* p0 = ld0 + (size_t)e * AGG_BK * 4096;
      const float* p1 = ld1 + (size_t)e * AGG_BK * 4096;
#pragma unroll
      for (int s = 0; s < 4; ++s) { pf[s] = ((const float4*)p0)[s]; pf[4 + s] = ((const float4*)p1)[s]; }
    }
  };
  auto stage_write = [&](unsigned short* dst) {
    if (!TC) {
#pragma unroll
      for (int s = 0; s < 4; ++s)
        *(short8*)&dst[sti * AGG_ST + stko + s * 8] = pack8(pf[2 * s], pf[2 * s + 1]);
    } else {
      const float* r0 = (const float*)&pf[0];   // row j0, 16 floats
      const float* r1 = (const float*)&pf[4];   // row j0+1
#pragma unroll
      for (int c = 0; c < 16; ++c) {
        unsigned v = (unsigned)f2bf(r0[c]) | ((unsigned)f2bf(r1[c]) << 16);
        *(unsigned*)&dst[(sti + c) * AGG_ST + j0] = v;  // element (i, j0/j0+1)
      }
    }
  };
  auto load_a = [&](int e, short8* d) {
#pragma unroll
    for (int sub = 0; sub < 4; ++sub)
#pragma unroll
      for (int mt = 0; mt < 2; ++mt)
        d[sub * 2 + mt] = *(const short8*)(arow[mt] + e * AGG_BK + sub * 32);
  };

  stage_load(e0);
  load_a(e0, a_cur);
  stage_write(lds);
  __syncthreads();

  for (int ei = 0; ei < ne; ++ei) {
    const int e = e0 + ei;
    unsigned short* cur = lds + (ei & 1) * AGG_BUF;
    unsigned short* nxt = lds + ((ei & 1) ^ 1) * AGG_BUF;

    if (ei < ne - 1) { stage_load(e + 1); load_a(e + 1, a_nxt); }

#pragma unroll
    for (int sub = 0; sub < 4; ++sub)
#pragma unroll
      for (int nt = 0; nt < 4; ++nt) {
        short8 bv = *(const short8*)&cur[(nt * 16 + r15) * AGG_ST + sub * 32 + q * 8];
        acc[0][nt] = MFMA(a_cur[sub * 2 + 0], bv, acc[0][nt]);
        acc[1][nt] = MFMA(a_cur[sub * 2 + 1], bv, acc[1][nt]);
      }

    if (ei < ne - 1) {
      stage_write(nxt);
#pragma unroll
      for (int i = 0; i < 8; ++i) a_cur[i] = a_nxt[i];
    }
    __syncthreads();
  }

  // epilogue: agg[b][i][v], 4 consecutive v per lane
#pragma unroll
  for (int mt = 0; mt < 2; ++mt) {
    const int v0 = w * 32 + mt * 16 + q * 4;
#pragma unroll
    for (int nt = 0; nt < 4; ++nt) {
      const int i = n0 + nt * 16 + r15;
      if (SPLIT) {
        float* aggf = (float*)agg;
        *(f32x4*)&aggf[(size_t)i * 128 + v0] = acc[mt][nt];   // 16B fp32 partial
      } else {
        unsigned short* aggh = (unsigned short*)agg;
        u16x4 o;
#pragma unroll
        for (int c = 0; c < 4; ++c) o[c] = f2bf(acc[mt][nt][c]);
        *(u16x4*)&aggh[(size_t)i * 128 + v0] = o;             // 8B bf16
      }
    }
  }
}

// split-K=2 variant: 1024 blocks -> 4 blocks/CU (LDS 4x34816=139KB fits;
// launch_bounds(256,4) caps VGPR at 128 so occupancy is grid-limited only).
__global__ __launch_bounds__(256, 4) void agg_split_kernel(
    const float* __restrict__ adj,
    const unsigned short* __restrict__ in_rep_t,
    const unsigned short* __restrict__ out_rep_t,
    float* __restrict__ in0, float* __restrict__ in1,
    float* __restrict__ out0, float* __restrict__ out1)
{
  __shared__ unsigned short lds[2 * AGG_BUF];
  const int id = blockIdx.x;            // [0,1024)
  const bool tc = id >= 512;
  const int t   = id & 511;
  const int kh  = t >> 8;               // K half: epochs [kh*16, kh*16+16)
  const int tt  = t & 255;
  const int b   = tt >> 6;
  const int n0  = (tt & 63) * 64;
  const float* adjb = adj + ((size_t)b << 24);
  const unsigned short* rep = (tc ? out_rep_t : in_rep_t) + ((size_t)b << 19);
  float* agg = (tc ? (kh ? out1 : out0) : (kh ? in1 : in0)) + ((size_t)b << 19);
  if (tc) agg_body<true,  true>(adjb, rep, agg, lds, n0, kh * 16, 16);
  else    agg_body<false, true>(adjb, rep, agg, lds, n0, kh * 16, 16);
}

// legacy split-1 path (used only if workspace is too small for fp32 partials)
__global__ __launch_bounds__(256, 2) void agg_kernel(
    const float* __restrict__ adj,
    const unsigned short* __restrict__ in_rep_t,
    const unsigned short* __restrict__ out_rep_t,
    unsigned short* __restrict__ in_agg,
    unsigned short* __restrict__ out_agg)
{
  __shared__ unsigned short lds[2 * AGG_BUF];
  const int id = blockIdx.x;
  const bool tc = (id >= 256);
  const int t  = id & 255;
  const int b  = t >> 6;
  const int n0 = (t & 63) * 64;
  const float* adjb = adj + ((size_t)b << 24);
  if (tc)
    agg_body<true,  false>(adjb, out_rep_t + ((size_t)b << 19), out_agg + ((size_t)b << 19), lds, n0, 0, 32);
  else
    agg_body<false, false>(adjb, in_rep_t + ((size_t)b << 19), in_agg + ((size_t)b << 19), lds, n0, 0, 32);
}

// ---------------------------------------------------------------------------
// Kernel 3: out[n,o] = tanh(sum_k upd[n,k] * W_upd[o,k] + b_upd[o]).
// Split variant: in_agg = in0+in1, out_agg = out0+out1 consumed as extra
// K-slices against the SAME W_upd columns (matmul linear in upd):
// 12 A-loads, 20 B-slices, fp32 agg inputs packed to bf16 in flight.
// ---------------------------------------------------------------------------
__global__ __launch_bounds__(256) void final_split_kernel(
    const float* __restrict__ in0, const float* __restrict__ in1,
    const unsigned short* __restrict__ node_rep,
    const float* __restrict__ out0, const float* __restrict__ out1,
    const float* __restrict__ W_upd,              // [128][384]
    const float* __restrict__ b_upd,              // [128]
    float* __restrict__ out)                      // [16384][128]
{
  const int tid  = threadIdx.x;
  const int lane = tid & 63;
  const int w    = tid >> 6;
  const int q    = lane >> 4;
  const int r15  = lane & 15;
  const int n0   = blockIdx.x * 32;

  f32x4 acc[2][2];
#pragma unroll
  for (int mt = 0; mt < 2; ++mt)
#pragma unroll
    for (int nt = 0; nt < 2; ++nt) acc[mt][nt] = (f32x4)0.0f;

#pragma unroll
  for (int ks = 0; ks < 12; ++ks) {
    const int s  = ks >> 2;              // 0:in 1:node 2:out
    const int kk = (ks & 3) * 32 + q * 8;
    short8 a[2];
#pragma unroll
    for (int mt = 0; mt < 2; ++mt) {
      const float* p = W_upd + (size_t)(w * 32 + mt * 16 + r15) * 384 + ks * 32 + q * 8;
      a[mt] = pack8(*(const float4*)p, *(const float4*)(p + 4));
    }
#pragma unroll
    for (int nt = 0; nt < 2; ++nt) {
      const int g = n0 + nt * 16 + r15;
      if (s == 1) {
        short8 bv = *(const short8*)&node_rep[(size_t)g * 128 + kk];
        acc[0][nt] = MFMA(a[0], bv, acc[0][nt]);
        acc[1][nt] = MFMA(a[1], bv, acc[1][nt]);
      } else {
        const float* p0 = ((s == 0) ? in0 : out0) + (size_t)g * 128 + kk;
        const float* p1 = ((s == 0) ? in1 : out1) + (size_t)g * 128 + kk;
        short8 bv0 = pack8(*(const float4*)p0, *(const float4*)(p0 + 4));
        acc[0][nt] = MFMA(a[0], bv0, acc[0][nt]);
        acc[1][nt] = MFMA(a[1], bv0, acc[1][nt]);
        short8 bv1 = pack8(*(const float4*)p1, *(const float4*)(p1 + 4));
        acc[0][nt] = MFMA(a[0], bv1, acc[0][nt]);
        acc[1][nt] = MFMA(a[1], bv1, acc[1][nt]);
      }
    }
  }

#pragma unroll
  for (int mt = 0; mt < 2; ++mt) {
    const int o0 = w * 32 + mt * 16 + q * 4;
#pragma unroll
    for (int nt = 0; nt < 2; ++nt) {
      const int g = n0 + nt * 16 + r15;
      f32x4 ov;
#pragma unroll
      for (int c = 0; c < 4; ++c) ov[c] = tanhf(acc[mt][nt][c] + b_upd[o0 + c]);
      *(f32x4*)&out[(size_t)g * 128 + o0] = ov;
    }
  }
}

// legacy final (bf16 aggs)
__global__ __launch_bounds__(256) void final_kernel(
    const unsigned short* __restrict__ in_agg,
    const unsigned short* __restrict__ node_rep,
    const unsigned short* __restrict__ out_agg,
    const float* __restrict__ W_upd,
    const float* __restrict__ b_upd,
    float* __restrict__ out)
{
  const int tid  = threadIdx.x;
  const int lane = tid & 63;
  const int w    = tid >> 6;
  const int q    = lane >> 4;
  const int r15  = lane & 15;
  const int n0   = blockIdx.x * 32;

  const unsigned short* srcs[3] = { in_agg, node_rep, out_agg };

  f32x4 acc[2][2];
#pragma unroll
  for (int mt = 0; mt < 2; ++mt)
#pragma unroll
    for (int nt = 0; nt < 2; ++nt) acc[mt][nt] = (f32x4)0.0f;

#pragma unroll
  for (int ks = 0; ks < 12; ++ks) {
    const unsigned short* src = srcs[ks >> 2];
    const int col0 = (ks & 3) * 32 + q * 8;
    short8 a[2];
#pragma unroll
    for (int mt = 0; mt < 2; ++mt) {
      const float* p = W_upd + (size_t)(w * 32 + mt * 16 + r15) * 384 + ks * 32 + q * 8;
      a[mt] = pack8(*(const float4*)p, *(const float4*)(p + 4));
    }
#pragma unroll
    for (int nt = 0; nt < 2; ++nt) {
      const int g = n0 + nt * 16 + r15;
      short8 bv = *(const short8*)&src[(size_t)g * 128 + col0];
      acc[0][nt] = MFMA(a[0], bv, acc[0][nt]);
      acc[1][nt] = MFMA(a[1], bv, acc[1][nt]);
    }
  }

#pragma unroll
  for (int mt = 0; mt < 2; ++mt) {
    const int o0 = w * 32 + mt * 16 + q * 4;
#pragma unroll
    for (int nt = 0; nt < 2; ++nt) {
      const int g = n0 + nt * 16 + r15;
      f32x4 ov;
#pragma unroll
      for (int c = 0; c < 4; ++c) ov[c] = tanhf(acc[mt][nt][c] + b_upd[o0 + c]);
      *(f32x4*)&out[(size_t)g * 128 + o0] = ov;
    }
  }
}

// ---------------------------------------------------------------------------
extern "C" void kernel_launch(void* const* d_in, const int* in_sizes, int n_in,
                              void* d_out, int out_size, void* d_ws, size_t ws_size,
                              hipStream_t stream) {
  (void)in_sizes; (void)n_in; (void)out_size;
  const float* nodes  = (const float*)d_in[0];
  const float* adj    = (const float*)d_in[1];
  const float* W_in   = (const float*)d_in[2];
  const float* b_in   = (const float*)d_in[3];
  const float* W_out  = (const float*)d_in[4];
  const float* b_out  = (const float*)d_in[5];
  const float* W_node = (const float*)d_in[6];
  const float* b_node = (const float*)d_in[7];
  const float* W_upd  = (const float*)d_in[8];
  const float* b_upd  = (const float*)d_in[9];
  float* out = (float*)d_out;

  unsigned short* ws = (unsigned short*)d_ws;
  const size_t SZ = (size_t)4 * 128 * 4096;   // shorts per bf16 [4][.][.] array
  const size_t FS = (size_t)4 * 4096 * 128;   // floats per fp32 agg array
  unsigned short* in_rep_t  = ws;
  unsigned short* out_rep_t = ws + SZ;
  unsigned short* node_rep  = ws + 2 * SZ;

  proj_kernel<<<dim3(256, 3), 256, 0, stream>>>(
      nodes, W_in, b_in, W_out, b_out, W_node, b_node,
      in_rep_t, out_rep_t, node_rep);

  const size_t need = 3 * SZ * sizeof(unsigned short) + 4 * FS * sizeof(float); // 44MB
  if (ws_size >= need) {
    float* fb = (float*)(ws + 3 * SZ);
    float* in0  = fb;
    float* in1  = fb + FS;
    float* out0 = fb + 2 * FS;
    float* out1 = fb + 3 * FS;
    agg_split_kernel<<<1024, 256, 0, stream>>>(adj, in_rep_t, out_rep_t,
                                               in0, in1, out0, out1);
    final_split_kernel<<<512, 256, 0, stream>>>(in0, in1, node_rep, out0, out1,
                                                W_upd, b_upd, out);
  } else {
    unsigned short* in_agg  = ws + 3 * SZ;
    unsigned short* out_agg = ws + 4 * SZ;
    agg_kernel<<<512, 256, 0, stream>>>(adj, in_rep_t, out_rep_t, in_agg, out_agg);
    final_kernel<<<512, 256, 0, stream>>>(in_agg, node_rep, out_agg, W_upd, b_upd, out);
  }
}